// Round 2
// baseline (427.264 us; speedup 1.0000x reference)
//
#include <hip/hip_runtime.h>

typedef __bf16 bf16;
typedef __attribute__((ext_vector_type(8))) __bf16 bf16x8;
typedef __attribute__((ext_vector_type(4))) __bf16 bf16x4;
typedef __attribute__((ext_vector_type(2))) __bf16 bf16x2;
typedef __attribute__((ext_vector_type(4))) float f32x4;

#define DEVINL __device__ __forceinline__

// Async global->LDS, 16B per lane.
DEVINL void gload_lds16(const bf16* g, bf16* l) {
    __builtin_amdgcn_global_load_lds(
        (__attribute__((address_space(1))) unsigned int*)(unsigned long long)g,
        (__attribute__((address_space(3))) unsigned int*)l,
        16, 0, 0);
}

// XCD-aware swizzle (uniform work): contiguous by-slab per XCD, bx fastest.
// Requires gridDim.y % 8 == 0.
DEVINL void xcd_swizzle(int& bx, int& by) {
    const int gx = gridDim.x, gy = gridDim.y;
    const int l = blockIdx.y * gx + blockIdx.x;
    const int xcd = l & 7;
    const int li = l >> 3;
    by = xcd * (gy >> 3) + li / gx;
    bx = li - (li / gx) * gx;
}

// Balanced XCD swizzle for causal grids (work ∝ by+1), gridDim.y==16 only:
// XCD x owns by = x and by = 15-x  ->  equal live work per XCD.
DEVINL void xcd_swizzle_bal(int& bx, int& by) {
    const int gx = gridDim.x, gy = gridDim.y;
    const int l = blockIdx.y * gx + blockIdx.x;
    const int xcd = l & 7;
    const int li = l >> 3;
    const int j = li / gx;            // slab 0 or 1
    bx = li - j * gx;
    by = j ? (gy - 1 - xcd) : xcd;
}

// ---------------------------------------------------------------- converts
__global__ __launch_bounds__(256) void cvt3_f32_to_bf16(
    const float* __restrict__ a, const float* __restrict__ b,
    const float* __restrict__ c, bf16* __restrict__ out, int n4) {
    int i = blockIdx.x * blockDim.x + threadIdx.x;
    if (i >= n4) return;
    const float* src = (blockIdx.z == 0) ? a : (blockIdx.z == 1) ? b : c;
    bf16* dst = out + (size_t)blockIdx.z * (size_t)n4 * 4;
    float4 f = ((const float4*)src)[i];
    bf16x4 o;
    o.x = (bf16)f.x; o.y = (bf16)f.y; o.z = (bf16)f.z; o.w = (bf16)f.w;
    ((bf16x4*)dst)[i] = o;
}

__global__ __launch_bounds__(256) void cvt4_f32_to_bf16(
    const float* __restrict__ a, const float* __restrict__ b,
    const float* __restrict__ c, const float* __restrict__ d,
    bf16* __restrict__ out, int n4) {
    int i = blockIdx.x * blockDim.x + threadIdx.x;
    if (i >= n4) return;
    const float* src = (blockIdx.z == 0) ? a : (blockIdx.z == 1) ? b
                     : (blockIdx.z == 2) ? c : d;
    bf16* dst = out + (size_t)blockIdx.z * (size_t)n4 * 4;
    float4 f = ((const float4*)src)[i];
    bf16x4 o;
    o.x = (bf16)f.x; o.y = (bf16)f.y; o.z = (bf16)f.z; o.w = (bf16)f.w;
    ((bf16x4*)dst)[i] = o;
}

// ---------------------------------------------------------------- transpose
__global__ __launch_bounds__(256) void transpose_bf16(
    const unsigned short* __restrict__ in, unsigned short* __restrict__ out,
    int R, int C) {
    __shared__ unsigned short t[64][65];
    const size_t bo = (size_t)blockIdx.z * R * C;
    const int r0 = blockIdx.y * 64, c0 = blockIdx.x * 64;
#pragma unroll
    for (int i = 0; i < 16; i++) {
        int lin = threadIdx.x + i * 256;
        int r = lin >> 6, c = lin & 63;
        t[r][c] = in[bo + (size_t)(r0 + r) * C + (c0 + c)];
    }
    __syncthreads();
#pragma unroll
    for (int i = 0; i < 16; i++) {
        int lin = threadIdx.x + i * 256;
        int r = lin >> 6, c = lin & 63;
        out[bo + (size_t)(c0 + r) * R + (r0 + c)] = t[c][r];
    }
}

// ---------------------------------------------------------------- bias fold
// bout[e] = dot(Wo[e,:], bv) + bo[e]   (one wave per e)
__global__ __launch_bounds__(256) void bias_fold(
    const float* __restrict__ Wo, const float* __restrict__ bv,
    const float* __restrict__ bo, float* __restrict__ bout) {
    const int e = blockIdx.x * 4 + (threadIdx.x >> 6);
    const int lane = threadIdx.x & 63;
    float s = 0.f;
    for (int k = lane; k < 1024; k += 64) s += Wo[e * 1024 + k] * bv[k];
#pragma unroll
    for (int off = 32; off > 0; off >>= 1) s += __shfl_xor(s, off, 64);
    if (lane == 0) bout[e] = s + bo[e];
}

// ------------------------------- GEMM 128x128, BK=32, LDS dbuf + XOR swizzle
// (kept for the small Wvo = Wo @ Wv 1024^3 GEMM only)
template <int EPI>
__global__ __launch_bounds__(256) void gemm_bt128(
    const bf16* __restrict__ A, const bf16* __restrict__ B,
    const float* __restrict__ bias0, const float* __restrict__ bias1,
    const float* __restrict__ bias2, void* __restrict__ Cv,
    int M, int N, int K,
    long long sA, long long sB, long long sC,
    float scale) {
    int bx, by;
    xcd_swizzle(bx, by);
    const int bz = blockIdx.z;
    const int m0 = by * 128, n0 = bx * 128;

    A += (size_t)bz * sA;
    B += (size_t)bz * sB;
    const float* bias = (bz == 0) ? bias0 : (bz == 1) ? bias1 : bias2;

    __shared__ __align__(16) bf16 As[2][128 * 32];
    __shared__ __align__(16) bf16 Bs[2][128 * 32];

    const int tid = threadIdx.x;
    const int wave = tid >> 6;
    const int lane = tid & 63;
    const int lr = lane & 15;
    const int lq = lane >> 4;
    const int wm = (wave >> 1) * 64;
    const int wn = (wave & 1) * 64;
    const int srow = lane >> 2;
    const int scol = ((lane & 3) ^ ((lane >> 3) & 3)) * 8;

    const bf16* gA = A + (size_t)(m0 + wave * 16 + srow) * K + scol;
    const bf16* gB = B + (size_t)(n0 + wave * 16 + srow) * K + scol;
    const size_t rowskip = (size_t)64 * K;
    const int rsw = (lq ^ ((lr >> 1) & 3)) * 8;

    f32x4 acc[4][4];
    const f32x4 fzero = {0.f, 0.f, 0.f, 0.f};
#pragma unroll
    for (int i = 0; i < 4; i++)
#pragma unroll
        for (int j = 0; j < 4; j++) acc[i][j] = fzero;

#define STAGE128(bufi)                                          \
    do {                                                        \
        gload_lds16(gA,           As[bufi] + wave * 512);       \
        gload_lds16(gA + rowskip, As[bufi] + (wave + 4) * 512); \
        gload_lds16(gB,           Bs[bufi] + wave * 512);       \
        gload_lds16(gB + rowskip, Bs[bufi] + (wave + 4) * 512); \
        gA += 32; gB += 32;                                     \
    } while (0)

    STAGE128(0);
    int cur = 0;
    for (int k0 = 0; k0 < K; k0 += 32) {
        __syncthreads();
        if (k0 + 32 < K) STAGE128(cur ^ 1);

        bf16x8 af[4], bfr[4];
#pragma unroll
        for (int i = 0; i < 4; i++)
            af[i] = *(const bf16x8*)(As[cur] + (wm + i * 16 + lr) * 32 + rsw);
#pragma unroll
        for (int j = 0; j < 4; j++)
            bfr[j] = *(const bf16x8*)(Bs[cur] + (wn + j * 16 + lr) * 32 + rsw);
#pragma unroll
        for (int i = 0; i < 4; i++)
#pragma unroll
            for (int j = 0; j < 4; j++)
                acc[i][j] = __builtin_amdgcn_mfma_f32_16x16x32_bf16(
                    af[i], bfr[j], acc[i][j], 0, 0, 0);
        cur ^= 1;
    }
#undef STAGE128

#pragma unroll
    for (int j = 0; j < 4; j++) {
        const int col = n0 + wn + j * 16 + lr;
        const float bb = bias ? bias[col] : 0.0f;
#pragma unroll
        for (int i = 0; i < 4; i++) {
            const int rowb = m0 + wm + i * 16 + lq * 4;
#pragma unroll
            for (int r = 0; r < 4; r++) {
                if (EPI == 0)
                    ((bf16*)Cv)[(size_t)bz * sC + (size_t)(rowb + r) * N + col] =
                        (bf16)(acc[i][j][r] * scale + bb);
                else
                    ((float*)Cv)[(size_t)bz * sC + (size_t)(rowb + r) * N + col] =
                        acc[i][j][r] * scale + bb;
            }
        }
    }
}

// -------------------- GEMM 256x256, BK=32, 512 thr, 4-buf single-barrier pipe
// Per iteration: { vmcnt(counted); s_barrier; STAGE(t+3); ds_read(t); MFMA(t) }.
// One barrier per K-step: a wave's ds_reads of tile t-1 complete before its
// MFMA(t-1) (compiler lgkmcnt), which precedes its arrival at barrier(t), so
// STAGE into buf[(t+3)&3]=buf[(t-1)&3] after barrier(t) is WAR-safe, and the
// DMA landing of tile t (staged at t-3) is ordered by each wave's own vmcnt +
// the barrier join. Stage-to-drain span = 3 iterations (~1500 cyc > HBM lat).
// Per-wave output 128x64: 12 ds_read_b128 feed 32 MFMA (cap ~60% MfmaUtil).
template <int EPI>
__global__ __launch_bounds__(512, 2) void gemm_pipe256(
    const bf16* __restrict__ A, const bf16* __restrict__ B,
    const float* __restrict__ bias0, const float* __restrict__ bias1,
    const float* __restrict__ bias2, void* __restrict__ Cv,
    int M, int N, int K,
    long long sA, long long sB, long long sC,
    float scale, int causal) {
    int bx, by;
    xcd_swizzle(bx, by);
    const int bz = blockIdx.z;
    const int m0 = by * 256, n0 = bx * 256;
    if (causal == 1 && n0 > m0 + 255) return;   // fully above diagonal
    const int NT = K >> 5;                       // BK=32 tiles

    A += (size_t)bz * sA;
    B += (size_t)bz * sB;
    const float* bias = (bz == 0) ? bias0 : (bz == 1) ? bias1 : bias2;

    // 4 buffers x (A 256x32 + B 256x32) bf16 = 4 x 32 KiB = 128 KiB.
    __shared__ __align__(16) bf16 As[4][256 * 32];
    __shared__ __align__(16) bf16 Bs[4][256 * 32];

    const int tid = threadIdx.x;
    const int wave = tid >> 6;            // 0..7
    const int lane = tid & 63;
    const int lr = lane & 15;
    const int lq = lane >> 4;
    const int wm = (wave >> 2) * 128;     // 2 wave-rows (0,128)
    const int wn = (wave & 3) * 64;       // 4 wave-cols (0..192)

    // staging: wave w covers rows [w*16,+16) and [128+w*16,+16) of A and B
    const int srow = lane >> 2;                              // 0..15
    const int scol = ((lane & 3) ^ ((lane >> 3) & 3)) * 8;   // pre-swizzled src
    const bf16* gA = A + (size_t)(m0 + wave * 16 + srow) * K + scol;
    const bf16* gB = B + (size_t)(n0 + wave * 16 + srow) * K + scol;
    const size_t rowskip = (size_t)128 * K;

    const int rsw = (lq ^ ((lr >> 1) & 3)) * 8;              // read swizzle

    f32x4 acc[8][4];
    const f32x4 fzero = {0.f, 0.f, 0.f, 0.f};
#pragma unroll
    for (int i = 0; i < 8; i++)
#pragma unroll
        for (int j = 0; j < 4; j++) acc[i][j] = fzero;

#define STAGEP(bufi, koff)                                                 \
    do {                                                                   \
        gload_lds16(gA + (koff),           As[bufi] + wave * 512);         \
        gload_lds16(gA + rowskip + (koff), As[bufi] + (wave + 8) * 512);   \
        gload_lds16(gB + (koff),           Bs[bufi] + wave * 512);         \
        gload_lds16(gB + rowskip + (koff), Bs[bufi] + (wave + 8) * 512);   \
    } while (0)

    if (NT > 0) STAGEP(0, 0);
    if (NT > 1) STAGEP(1, 32);
    if (NT > 2) STAGEP(2, 64);

    for (int t = 0; t < NT; ++t) {
        const int nf = NT - t;      // tiles currently in flight = min(nf,3)
        if (nf > 2)       asm volatile("s_waitcnt vmcnt(8)" ::: "memory");
        else if (nf == 2) asm volatile("s_waitcnt vmcnt(4)" ::: "memory");
        else              asm volatile("s_waitcnt vmcnt(0)" ::: "memory");
        __builtin_amdgcn_s_barrier();
        asm volatile("" ::: "memory");   // keep ds_reads below the barrier

        if (t + 3 < NT) STAGEP((t + 3) & 3, (t + 3) * 32);

        const int bfi = t & 3;
        bf16x8 af[8], bfr[4];
#pragma unroll
        for (int i = 0; i < 8; i++)
            af[i] = *(const bf16x8*)(As[bfi] + (wm + i * 16 + lr) * 32 + rsw);
#pragma unroll
        for (int j = 0; j < 4; j++)
            bfr[j] = *(const bf16x8*)(Bs[bfi] + (wn + j * 16 + lr) * 32 + rsw);

        __builtin_amdgcn_s_setprio(1);
#pragma unroll
        for (int i = 0; i < 8; i++)
#pragma unroll
            for (int j = 0; j < 4; j++)
                acc[i][j] = __builtin_amdgcn_mfma_f32_16x16x32_bf16(
                    af[i], bfr[j], acc[i][j], 0, 0, 0);
        __builtin_amdgcn_s_setprio(0);
    }
#undef STAGEP

#pragma unroll
    for (int j = 0; j < 4; j++) {
        const int col = n0 + wn + j * 16 + lr;
        const float bb = bias ? bias[col] : 0.0f;
#pragma unroll
        for (int i = 0; i < 8; i++) {
            const int rowb = m0 + wm + i * 16 + lq * 4;
#pragma unroll
            for (int r = 0; r < 4; r++) {
                if (EPI == 0)
                    ((bf16*)Cv)[(size_t)bz * sC + (size_t)(rowb + r) * N + col] =
                        (bf16)(acc[i][j][r] * scale + bb);
                else
                    ((float*)Cv)[(size_t)bz * sC + (size_t)(rowb + r) * N + col] =
                        acc[i][j][r] * scale + bb;
            }
        }
    }
}

// -------------------- GEMM 128x128, BK=32, 256 thr, 4-buf single-barrier pipe
// Same schedule as gemm_pipe256 but 64 KiB LDS -> 2 blocks/CU (TLP latency
// hiding + fine-grained causal balance). For PV: causal=2 trims K to m0+128;
// balanced pair swizzle gives each XCD uniform total K (2176).
__global__ __launch_bounds__(256, 2) void gemm_pv128(
    const bf16* __restrict__ A, const bf16* __restrict__ B,
    const float* __restrict__ bias, float* __restrict__ C,
    int M, int N, int K,
    long long sA, long long sB, long long sC,
    float scale) {
    int bx, by;
    xcd_swizzle_bal(bx, by);
    const int bz = blockIdx.z;
    const int m0 = by * 128, n0 = bx * 128;
    int Keff = m0 + 128; if (Keff > K) Keff = K;
    const int NT = Keff >> 5;

    A += (size_t)bz * sA;
    B += (size_t)bz * sB;

    // 4 buffers x (A 128x32 + B 128x32) bf16 = 4 x 16 KiB = 64 KiB.
    __shared__ __align__(16) bf16 As[4][128 * 32];
    __shared__ __align__(16) bf16 Bs[4][128 * 32];

    const int tid = threadIdx.x;
    const int wave = tid >> 6;            // 0..3
    const int lane = tid & 63;
    const int lr = lane & 15;
    const int lq = lane >> 4;
    const int wm = (wave >> 1) * 64;
    const int wn = (wave & 1) * 64;

    const int srow = lane >> 2;
    const int scol = ((lane & 3) ^ ((lane >> 3) & 3)) * 8;
    const bf16* gA = A + (size_t)(m0 + wave * 16 + srow) * K + scol;
    const bf16* gB = B + (size_t)(n0 + wave * 16 + srow) * K + scol;
    const size_t rowskip = (size_t)64 * K;

    const int rsw = (lq ^ ((lr >> 1) & 3)) * 8;

    f32x4 acc[4][4];
    const f32x4 fzero = {0.f, 0.f, 0.f, 0.f};
#pragma unroll
    for (int i = 0; i < 4; i++)
#pragma unroll
        for (int j = 0; j < 4; j++) acc[i][j] = fzero;

#define STAGEV(bufi, koff)                                                 \
    do {                                                                   \
        gload_lds16(gA + (koff),           As[bufi] + wave * 512);         \
        gload_lds16(gA + rowskip + (koff), As[bufi] + (wave + 4) * 512);   \
        gload_lds16(gB + (koff),           Bs[bufi] + wave * 512);         \
        gload_lds16(gB + rowskip + (koff), Bs[bufi] + (wave + 4) * 512);   \
    } while (0)

    if (NT > 0) STAGEV(0, 0);
    if (NT > 1) STAGEV(1, 32);
    if (NT > 2) STAGEV(2, 64);

    for (int t = 0; t < NT; ++t) {
        const int nf = NT - t;
        if (nf > 2)       asm volatile("s_waitcnt vmcnt(8)" ::: "memory");
        else if (nf == 2) asm volatile("s_waitcnt vmcnt(4)" ::: "memory");
        else              asm volatile("s_waitcnt vmcnt(0)" ::: "memory");
        __builtin_amdgcn_s_barrier();
        asm volatile("" ::: "memory");

        if (t + 3 < NT) STAGEV((t + 3) & 3, (t + 3) * 32);

        const int bfi = t & 3;
        bf16x8 af[4], bfr[4];
#pragma unroll
        for (int i = 0; i < 4; i++)
            af[i] = *(const bf16x8*)(As[bfi] + (wm + i * 16 + lr) * 32 + rsw);
#pragma unroll
        for (int j = 0; j < 4; j++)
            bfr[j] = *(const bf16x8*)(Bs[bfi] + (wn + j * 16 + lr) * 32 + rsw);

        __builtin_amdgcn_s_setprio(1);
#pragma unroll
        for (int i = 0; i < 4; i++)
#pragma unroll
            for (int j = 0; j < 4; j++)
                acc[i][j] = __builtin_amdgcn_mfma_f32_16x16x32_bf16(
                    af[i], bfr[j], acc[i][j], 0, 0, 0);
        __builtin_amdgcn_s_setprio(0);
    }
#undef STAGEV

#pragma unroll
    for (int j = 0; j < 4; j++) {
        const int col = n0 + wn + j * 16 + lr;
        const float bb = bias[col];
#pragma unroll
        for (int i = 0; i < 4; i++) {
            const int rowb = m0 + wm + i * 16 + lq * 4;
#pragma unroll
            for (int r = 0; r < 4; r++)
                C[(size_t)bz * sC + (size_t)(rowb + r) * N + col] =
                    acc[i][j][r] * scale + bb;
        }
    }
}

// ---------------------------------------------------------------- softmax
__global__ __launch_bounds__(256) void softmax_causal(
    const bf16* __restrict__ Sc, bf16* __restrict__ P, int S) {
    const int row = blockIdx.x;          // b*S + q
    const int q = row & (S - 1);
    const bf16* src = Sc + (size_t)row * S;
    bf16* dst = P + (size_t)row * S;
    const int L = q + 1;
    const int tid = threadIdx.x;

    float v[8];
    float mx = -3.0e38f;
#pragma unroll
    for (int i = 0; i < 4; i++) {
        int k = (i * 256 + tid) * 2;
        bf16x2 u = ((const bf16x2*)src)[i * 256 + tid];
        v[2 * i]     = (k < L)     ? (float)u.x : -3.0e38f;
        v[2 * i + 1] = (k + 1 < L) ? (float)u.y : -3.0e38f;
        mx = fmaxf(mx, fmaxf(v[2 * i], v[2 * i + 1]));
    }
#pragma unroll
    for (int off = 32; off > 0; off >>= 1) mx = fmaxf(mx, __shfl_xor(mx, off, 64));
    __shared__ float redm[4], reds[4];
    if ((tid & 63) == 0) redm[tid >> 6] = mx;
    __syncthreads();
    mx = fmaxf(fmaxf(redm[0], redm[1]), fmaxf(redm[2], redm[3]));

    float sum = 0.f;
#pragma unroll
    for (int i = 0; i < 8; i++) {
        float e = (v[i] > -1.0e38f) ? __expf(v[i] - mx) : 0.f;
        v[i] = e;
        sum += e;
    }
#pragma unroll
    for (int off = 32; off > 0; off >>= 1) sum += __shfl_xor(sum, off, 64);
    if ((tid & 63) == 0) reds[tid >> 6] = sum;
    __syncthreads();
    sum = reds[0] + reds[1] + reds[2] + reds[3];
    const float inv = 1.0f / sum;
#pragma unroll
    for (int i = 0; i < 4; i++) {
        bf16x2 o;
        o.x = (bf16)(v[2 * i] * inv);
        o.y = (bf16)(v[2 * i + 1] * inv);
        ((bf16x2*)dst)[i * 256 + tid] = o;
    }
}

// ---------------------------------------------------------------- launch
extern "C" void kernel_launch(void* const* d_in, const int* in_sizes, int n_in,
                              void* d_out, int out_size, void* d_ws, size_t ws_size,
                              hipStream_t stream) {
    const int B = 4, S = 2048, E = 1024;
    const size_t SBE = (size_t)B * S * E;   // 8,388,608
    const size_t EE = (size_t)E * E;        // 1,048,576

    const float* q_in = (const float*)d_in[0];
    const float* k_in = (const float*)d_in[1];
    const float* v_in = (const float*)d_in[2];
    // d_in[3] = mask (tril) — causality handled by index math
    const float* Wq = (const float*)d_in[4];
    const float* bq = (const float*)d_in[5];
    const float* Wk = (const float*)d_in[6];
    const float* bk = (const float*)d_in[7];
    const float* Wv = (const float*)d_in[8];
    const float* bv = (const float*)d_in[9];
    const float* Wo = (const float*)d_in[10];
    const float* bo = (const float*)d_in[11];

    char* ws = (char*)d_ws;
    // Region A (67 MB), time-multiplexed:
    //   [0,48M): qkvb (phase 1), then Sc bf16 [0,33.5M) (phase 2)
    //   [48M,50M): WvT (bf16 Wv^T, live during Wvo prep)
    //   [50M,+4KB): bout
    bf16* qkvb = (bf16*)ws;
    bf16* Sc = (bf16*)ws;
    bf16* WvT = (bf16*)(ws + 3 * SBE * 2);
    float* bout = (float*)(ws + 3 * SBE * 2 + EE * 2);
    char* p = ws + (size_t)B * S * S * 4;
    bf16* QKVb = (bf16*)p; p += 3 * SBE * 2;   // Qb|Kb|VW contiguous
    bf16* VWt = (bf16*)p; p += SBE * 2;
    bf16* Pb = (bf16*)p; p += (size_t)B * S * S * 2;
    bf16* Wb = (bf16*)p; p += 4 * EE * 2;      // Wq|Wk|Wv(->Wvo)|Wo

    bf16* Qb = QKVb;
    bf16* Kb = QKVb + SBE;
    bf16* VW = QKVb + 2 * SBE;
    bf16* Wob = Wb + 3 * EE;
    bf16* Wvo = Wb + 2 * EE;   // Wv slot overwritten by Wvo after transpose

    dim3 blk(256), blk512(512);

    // 1. converts
    dim3 gcvt3((int)(SBE / 4 / 256), 1, 3);
    cvt3_f32_to_bf16<<<gcvt3, blk, 0, stream>>>(q_in, k_in, v_in, qkvb, (int)(SBE / 4));
    dim3 gcvt4((int)(EE / 4 / 256), 1, 4);
    cvt4_f32_to_bf16<<<gcvt4, blk, 0, stream>>>(Wq, Wk, Wv, Wo, Wb, (int)(EE / 4));

    // 2. WvT = Wv^T ; Wvo = Wo @ Wv (B^T GEMM with B=WvT) ; bout = Wo bv + bo
    dim3 gtw(16, 16, 1);
    transpose_bf16<<<gtw, blk, 0, stream>>>((const unsigned short*)(Wb + 2 * EE),
                                            (unsigned short*)WvT, E, E);
    dim3 gwvo(E / 128, E / 128, 1);
    gemm_bt128<0><<<gwvo, blk, 0, stream>>>(Wob, WvT, nullptr, nullptr, nullptr,
                                            Wvo, E, E, E, 0, 0, 0, 1.f);
    bias_fold<<<256, blk, 0, stream>>>(Wo, bv, bo, bout);

    // 3. fused projections: z=0 Q (bq), z=1 K (bk), z=2 VW = v_in @ Wvo^T
    dim3 gproj(E / 256, (B * S) / 256, 3);
    gemm_pipe256<0><<<gproj, blk512, 0, stream>>>(qkvb, Wb, bq, bk, nullptr, QKVb,
                                                  B * S, E, E,
                                                  (long long)SBE, (long long)EE,
                                                  (long long)SBE, 1.f, 0);

    // 4. VW^T per batch: [S,E] -> [E,S]
    dim3 gt(E / 64, S / 64, B);
    transpose_bf16<<<gt, blk, 0, stream>>>((const unsigned short*)VW,
                                           (unsigned short*)VWt, S, E);

    // 5. scores = Q K^T / 32 -> bf16 (causal tile skip; 144 live blocks
    //    of 256 -> single concurrent round)
    dim3 gsc(S / 256, S / 256, B);
    gemm_pipe256<0><<<gsc, blk512, 0, stream>>>(Qb, Kb, nullptr, nullptr, nullptr, Sc,
                                                S, S, E,
                                                (long long)S * E, (long long)S * E,
                                                (long long)S * S, 0.03125f, 1);

    // 6. causal softmax -> bf16 probs (zeros above diagonal)
    softmax_causal<<<B * S, blk, 0, stream>>>(Sc, Pb, S);

    // 7. out = P @ VW + bout, causal K-trim (Keff = m0+128), 2 blocks/CU,
    //    XCD-pair-balanced (each XCD gets uniform total K)
    dim3 gpv(E / 128, S / 128, B);
    gemm_pv128<<<gpv, blk, 0, stream>>>(Pb, VWt, bout, (float*)d_out, S, E, S,
                                        (long long)S * S, (long long)E * S,
                                        (long long)S * E, 1.f);
}

// Round 3
// 394.804 us; speedup vs baseline: 1.0822x; 1.0822x over previous
//
#include <hip/hip_runtime.h>

typedef __bf16 bf16;
typedef __attribute__((ext_vector_type(8))) __bf16 bf16x8;
typedef __attribute__((ext_vector_type(4))) __bf16 bf16x4;
typedef __attribute__((ext_vector_type(2))) __bf16 bf16x2;
typedef __attribute__((ext_vector_type(4))) float f32x4;

#define DEVINL __device__ __forceinline__

// Async global->LDS, 16B per lane.
DEVINL void gload_lds16(const bf16* g, bf16* l) {
    __builtin_amdgcn_global_load_lds(
        (__attribute__((address_space(1))) unsigned int*)(unsigned long long)g,
        (__attribute__((address_space(3))) unsigned int*)l,
        16, 0, 0);
}

// XCD-aware swizzle (uniform work): contiguous by-slab per XCD, bx fastest.
// Requires gridDim.y % 8 == 0.
DEVINL void xcd_swizzle(int& bx, int& by) {
    const int gx = gridDim.x, gy = gridDim.y;
    const int l = blockIdx.y * gx + blockIdx.x;
    const int xcd = l & 7;
    const int li = l >> 3;
    by = xcd * (gy >> 3) + li / gx;
    bx = li - (li / gx) * gx;
}

// Balanced XCD swizzle for causal grids (work ∝ by+1), gridDim.y==16 only:
// XCD x owns by = x and by = 15-x  ->  equal live work per XCD.
DEVINL void xcd_swizzle_bal(int& bx, int& by) {
    const int gx = gridDim.x, gy = gridDim.y;
    const int l = blockIdx.y * gx + blockIdx.x;
    const int xcd = l & 7;
    const int li = l >> 3;
    const int j = li / gx;            // slab 0 or 1
    bx = li - j * gx;
    by = j ? (gy - 1 - xcd) : xcd;
}

// ---------------------------------------------------------------- converts
__global__ __launch_bounds__(256) void cvt3_f32_to_bf16(
    const float* __restrict__ a, const float* __restrict__ b,
    const float* __restrict__ c, bf16* __restrict__ out, int n4) {
    int i = blockIdx.x * blockDim.x + threadIdx.x;
    if (i >= n4) return;
    const float* src = (blockIdx.z == 0) ? a : (blockIdx.z == 1) ? b : c;
    bf16* dst = out + (size_t)blockIdx.z * (size_t)n4 * 4;
    float4 f = ((const float4*)src)[i];
    bf16x4 o;
    o.x = (bf16)f.x; o.y = (bf16)f.y; o.z = (bf16)f.z; o.w = (bf16)f.w;
    ((bf16x4*)dst)[i] = o;
}

__global__ __launch_bounds__(256) void cvt4_f32_to_bf16(
    const float* __restrict__ a, const float* __restrict__ b,
    const float* __restrict__ c, const float* __restrict__ d,
    bf16* __restrict__ out, int n4) {
    int i = blockIdx.x * blockDim.x + threadIdx.x;
    if (i >= n4) return;
    const float* src = (blockIdx.z == 0) ? a : (blockIdx.z == 1) ? b
                     : (blockIdx.z == 2) ? c : d;
    bf16* dst = out + (size_t)blockIdx.z * (size_t)n4 * 4;
    float4 f = ((const float4*)src)[i];
    bf16x4 o;
    o.x = (bf16)f.x; o.y = (bf16)f.y; o.z = (bf16)f.z; o.w = (bf16)f.w;
    ((bf16x4*)dst)[i] = o;
}

// ---------------------------------------------------------------- transpose
__global__ __launch_bounds__(256) void transpose_bf16(
    const unsigned short* __restrict__ in, unsigned short* __restrict__ out,
    int R, int C) {
    __shared__ unsigned short t[64][65];
    const size_t bo = (size_t)blockIdx.z * R * C;
    const int r0 = blockIdx.y * 64, c0 = blockIdx.x * 64;
#pragma unroll
    for (int i = 0; i < 16; i++) {
        int lin = threadIdx.x + i * 256;
        int r = lin >> 6, c = lin & 63;
        t[r][c] = in[bo + (size_t)(r0 + r) * C + (c0 + c)];
    }
    __syncthreads();
#pragma unroll
    for (int i = 0; i < 16; i++) {
        int lin = threadIdx.x + i * 256;
        int r = lin >> 6, c = lin & 63;
        out[bo + (size_t)(c0 + r) * R + (r0 + c)] = t[c][r];
    }
}

// ---------------------------------------------------------------- bias fold
// bout[e] = dot(Wo[e,:], bv) + bo[e]   (one wave per e)
__global__ __launch_bounds__(256) void bias_fold(
    const float* __restrict__ Wo, const float* __restrict__ bv,
    const float* __restrict__ bo, float* __restrict__ bout) {
    const int e = blockIdx.x * 4 + (threadIdx.x >> 6);
    const int lane = threadIdx.x & 63;
    float s = 0.f;
    for (int k = lane; k < 1024; k += 64) s += Wo[e * 1024 + k] * bv[k];
#pragma unroll
    for (int off = 32; off > 0; off >>= 1) s += __shfl_xor(s, off, 64);
    if (lane == 0) bout[e] = s + bo[e];
}

// ------------------------------- GEMM 128x128, BK=32, LDS dbuf + XOR swizzle
// (kept for the small Wvo = Wo @ Wv 1024^3 GEMM only)
template <int EPI>
__global__ __launch_bounds__(256) void gemm_bt128(
    const bf16* __restrict__ A, const bf16* __restrict__ B,
    const float* __restrict__ bias0, const float* __restrict__ bias1,
    const float* __restrict__ bias2, void* __restrict__ Cv,
    int M, int N, int K,
    long long sA, long long sB, long long sC,
    float scale) {
    int bx, by;
    xcd_swizzle(bx, by);
    const int bz = blockIdx.z;
    const int m0 = by * 128, n0 = bx * 128;

    A += (size_t)bz * sA;
    B += (size_t)bz * sB;
    const float* bias = (bz == 0) ? bias0 : (bz == 1) ? bias1 : bias2;

    __shared__ __align__(16) bf16 As[2][128 * 32];
    __shared__ __align__(16) bf16 Bs[2][128 * 32];

    const int tid = threadIdx.x;
    const int wave = tid >> 6;
    const int lane = tid & 63;
    const int lr = lane & 15;
    const int lq = lane >> 4;
    const int wm = (wave >> 1) * 64;
    const int wn = (wave & 1) * 64;
    const int srow = lane >> 2;
    const int scol = ((lane & 3) ^ ((lane >> 3) & 3)) * 8;

    const bf16* gA = A + (size_t)(m0 + wave * 16 + srow) * K + scol;
    const bf16* gB = B + (size_t)(n0 + wave * 16 + srow) * K + scol;
    const size_t rowskip = (size_t)64 * K;
    const int rsw = (lq ^ ((lr >> 1) & 3)) * 8;

    f32x4 acc[4][4];
    const f32x4 fzero = {0.f, 0.f, 0.f, 0.f};
#pragma unroll
    for (int i = 0; i < 4; i++)
#pragma unroll
        for (int j = 0; j < 4; j++) acc[i][j] = fzero;

#define STAGE128(bufi)                                          \
    do {                                                        \
        gload_lds16(gA,           As[bufi] + wave * 512);       \
        gload_lds16(gA + rowskip, As[bufi] + (wave + 4) * 512); \
        gload_lds16(gB,           Bs[bufi] + wave * 512);       \
        gload_lds16(gB + rowskip, Bs[bufi] + (wave + 4) * 512); \
        gA += 32; gB += 32;                                     \
    } while (0)

    STAGE128(0);
    int cur = 0;
    for (int k0 = 0; k0 < K; k0 += 32) {
        __syncthreads();
        if (k0 + 32 < K) STAGE128(cur ^ 1);

        bf16x8 af[4], bfr[4];
#pragma unroll
        for (int i = 0; i < 4; i++)
            af[i] = *(const bf16x8*)(As[cur] + (wm + i * 16 + lr) * 32 + rsw);
#pragma unroll
        for (int j = 0; j < 4; j++)
            bfr[j] = *(const bf16x8*)(Bs[cur] + (wn + j * 16 + lr) * 32 + rsw);
#pragma unroll
        for (int i = 0; i < 4; i++)
#pragma unroll
            for (int j = 0; j < 4; j++)
                acc[i][j] = __builtin_amdgcn_mfma_f32_16x16x32_bf16(
                    af[i], bfr[j], acc[i][j], 0, 0, 0);
        cur ^= 1;
    }
#undef STAGE128

#pragma unroll
    for (int j = 0; j < 4; j++) {
        const int col = n0 + wn + j * 16 + lr;
        const float bb = bias ? bias[col] : 0.0f;
#pragma unroll
        for (int i = 0; i < 4; i++) {
            const int rowb = m0 + wm + i * 16 + lq * 4;
#pragma unroll
            for (int r = 0; r < 4; r++) {
                if (EPI == 0)
                    ((bf16*)Cv)[(size_t)bz * sC + (size_t)(rowb + r) * N + col] =
                        (bf16)(acc[i][j][r] * scale + bb);
                else
                    ((float*)Cv)[(size_t)bz * sC + (size_t)(rowb + r) * N + col] =
                        acc[i][j][r] * scale + bb;
            }
        }
    }
}

// ---------------- GEMM 128x256, BK=32, 512 thr, 4-buf template-phase pipe
// One template phase per K-tile (T3+T4+T5, m201 schedule mapped to this
// geometry):  { 8x ds_read(t) ; 3x gload_lds(t+3) ; s_waitcnt vmcnt(counted)
//               ; s_barrier ; 16x MFMA(t) ; s_barrier }
// - reads issued BEFORE barrier1, consumed after (compiler lgkmcnt) -> LDS
//   latency hides under the barrier join.
// - counted vmcnt (6/3/0) never drains the DMA queue in steady state:
//   tiles t+2,t+3 stay in flight across the barrier.
// - barrier1 (after each wave's own vmcnt) => tile t+1 resident for ALL
//   waves before iter t+1's reads.
// - barrier2 => every wave's reads(t) completed (own lgkm before MFMA,
//   before barrier2) before any wave's STAGE(t+4) overwrites buf[t&3].
template <int EPI>
__global__ __launch_bounds__(512) void gemm_pipe(
    const bf16* __restrict__ A, const bf16* __restrict__ B,
    const float* __restrict__ bias0, const float* __restrict__ bias1,
    const float* __restrict__ bias2, void* __restrict__ Cv,
    int M, int N, int K,
    long long sA, long long sB, long long sC,
    float scale, int causal) {
    int bx, by;
    if (causal) xcd_swizzle_bal(bx, by);
    else        xcd_swizzle(bx, by);
    const int bz = blockIdx.z;
    const int m0 = by * 128, n0 = bx * 256;
    if (causal == 1 && n0 > m0 + 127) return;   // fully above diagonal
    const int NT = K >> 5;                       // BK=32 tiles (>=4 here)

    A += (size_t)bz * sA;
    B += (size_t)bz * sB;
    const float* bias = (bz == 0) ? bias0 : (bz == 1) ? bias1 : bias2;

    // 4 buffers: A[128][32] (8KB) + B[256][32] (16KB) each -> 96 KiB total.
    __shared__ __align__(16) bf16 As[4][128 * 32];
    __shared__ __align__(16) bf16 Bs[4][256 * 32];

    const int tid = threadIdx.x;
    const int wave = tid >> 6;            // 0..7
    const int lane = tid & 63;
    const int lr = lane & 15;
    const int lq = lane >> 4;
    const int wm = (wave >> 2) * 64;      // 2 wave-rows  (0,64)
    const int wn = (wave & 3) * 64;       // 4 wave-cols  (0..192)

    // staging: per tile, wave w covers A rows [w*16,+16), B rows [w*32,+32)
    const int srow = lane >> 2;                              // 0..15
    const int scol = ((lane & 3) ^ ((lane >> 3) & 3)) * 8;   // pre-swizzled src
    const bf16* gA  = A + (size_t)(m0 + wave * 16 + srow) * K + scol;
    const bf16* gB0 = B + (size_t)(n0 + wave * 32 + srow) * K + scol;
    const size_t rowskip = (size_t)16 * K;

    const int rsw = (lq ^ ((lr >> 1) & 3)) * 8;              // read swizzle

    f32x4 acc[4][4];
    const f32x4 fzero = {0.f, 0.f, 0.f, 0.f};
#pragma unroll
    for (int i = 0; i < 4; i++)
#pragma unroll
        for (int j = 0; j < 4; j++) acc[i][j] = fzero;

#define STAGEP(bufi, koff)                                               \
    do {                                                                 \
        gload_lds16(gA + (koff),            As[bufi] + wave * 512);      \
        gload_lds16(gB0 + (koff),           Bs[bufi] + wave * 1024);     \
        gload_lds16(gB0 + rowskip + (koff), Bs[bufi] + wave * 1024 + 512); \
    } while (0)

    // prologue: stage tiles 0..2; tile 0 resident after vmcnt(6)+barrier
    STAGEP(0, 0);
    STAGEP(1, 32);
    STAGEP(2, 64);
    asm volatile("s_waitcnt vmcnt(6)" ::: "memory");
    __builtin_amdgcn_s_barrier();

    for (int t = 0; t < NT; ++t) {
        const int bfi = t & 3;

        // 1. register fragments of tile t (resident per prev vmcnt+barrier)
        bf16x8 af[4], bfr[4];
#pragma unroll
        for (int i = 0; i < 4; i++)
            af[i] = *(const bf16x8*)(As[bfi] + (wm + i * 16 + lr) * 32 + rsw);
#pragma unroll
        for (int j = 0; j < 4; j++)
            bfr[j] = *(const bf16x8*)(Bs[bfi] + (wn + j * 16 + lr) * 32 + rsw);

        // 2. prefetch tile t+3 into buf freed by tile t-1 (WAR via barrier2)
        if (t + 3 < NT) STAGEP((t + 3) & 3, (t + 3) * 32);

        // 3. counted vmcnt: tile t+1 resident after the join; newer stages
        //    remain in flight (never drain to 0 in steady state)
        const int rem = NT - 1 - t;   // staged-but-unwaited tiles after step 2
        if (rem >= 3)      asm volatile("s_waitcnt vmcnt(6)" ::: "memory");
        else if (rem == 2) asm volatile("s_waitcnt vmcnt(3)" ::: "memory");
        else if (rem == 1) asm volatile("s_waitcnt vmcnt(0)" ::: "memory");
        __builtin_amdgcn_s_barrier();
        __builtin_amdgcn_sched_barrier(0);

        // 4. MFMA cluster (compiler inserts lgkmcnt for af/bfr)
        __builtin_amdgcn_s_setprio(1);
#pragma unroll
        for (int i = 0; i < 4; i++)
#pragma unroll
            for (int j = 0; j < 4; j++)
                acc[i][j] = __builtin_amdgcn_mfma_f32_16x16x32_bf16(
                    af[i], bfr[j], acc[i][j], 0, 0, 0);
        __builtin_amdgcn_s_setprio(0);
        __builtin_amdgcn_s_barrier();
    }
#undef STAGEP

#pragma unroll
    for (int j = 0; j < 4; j++) {
        const int col = n0 + wn + j * 16 + lr;
        const float bb = bias ? bias[col] : 0.0f;
#pragma unroll
        for (int i = 0; i < 4; i++) {
            const int rowb = m0 + wm + i * 16 + lq * 4;
#pragma unroll
            for (int r = 0; r < 4; r++) {
                if (EPI == 0)
                    ((bf16*)Cv)[(size_t)bz * sC + (size_t)(rowb + r) * N + col] =
                        (bf16)(acc[i][j][r] * scale + bb);
                else
                    ((float*)Cv)[(size_t)bz * sC + (size_t)(rowb + r) * N + col] =
                        acc[i][j][r] * scale + bb;
            }
        }
    }
}

// ---------------- GEMM 128x128, BK=32, 256 thr, 4-buf template-phase pipe
// Same schedule as gemm_pipe; 64 KiB LDS -> 2 blocks/CU so causal K-trimmed
// blocks PAIR on a CU (trim reduces makespan only at >=2 blocks/CU).
// PV: Keff = m0+128; balanced pair swizzle -> uniform total K per XCD.
__global__ __launch_bounds__(256, 2) void gemm_pv128(
    const bf16* __restrict__ A, const bf16* __restrict__ B,
    const float* __restrict__ bias, float* __restrict__ C,
    int M, int N, int K,
    long long sA, long long sB, long long sC,
    float scale) {
    int bx, by;
    xcd_swizzle_bal(bx, by);
    const int bz = blockIdx.z;
    const int m0 = by * 128, n0 = bx * 128;
    int Keff = m0 + 128; if (Keff > K) Keff = K;
    const int NT = Keff >> 5;   // >= 4

    A += (size_t)bz * sA;
    B += (size_t)bz * sB;

    // 4 buffers x (A 128x32 + B 128x32) bf16 = 64 KiB.
    __shared__ __align__(16) bf16 As[4][128 * 32];
    __shared__ __align__(16) bf16 Bs[4][128 * 32];

    const int tid = threadIdx.x;
    const int wave = tid >> 6;            // 0..3
    const int lane = tid & 63;
    const int lr = lane & 15;
    const int lq = lane >> 4;
    const int wm = (wave >> 1) * 64;
    const int wn = (wave & 1) * 64;

    const int srow = lane >> 2;
    const int scol = ((lane & 3) ^ ((lane >> 3) & 3)) * 8;
    const bf16* gA = A + (size_t)(m0 + wave * 16 + srow) * K + scol;
    const bf16* gB = B + (size_t)(n0 + wave * 16 + srow) * K + scol;
    const size_t rowskip = (size_t)64 * K;

    const int rsw = (lq ^ ((lr >> 1) & 3)) * 8;

    f32x4 acc[4][4];
    const f32x4 fzero = {0.f, 0.f, 0.f, 0.f};
#pragma unroll
    for (int i = 0; i < 4; i++)
#pragma unroll
        for (int j = 0; j < 4; j++) acc[i][j] = fzero;

#define STAGEV(bufi, koff)                                                 \
    do {                                                                   \
        gload_lds16(gA + (koff),           As[bufi] + wave * 512);         \
        gload_lds16(gA + rowskip + (koff), As[bufi] + (wave + 4) * 512);   \
        gload_lds16(gB + (koff),           Bs[bufi] + wave * 512);         \
        gload_lds16(gB + rowskip + (koff), Bs[bufi] + (wave + 4) * 512);   \
    } while (0)

    STAGEV(0, 0);
    STAGEV(1, 32);
    STAGEV(2, 64);
    asm volatile("s_waitcnt vmcnt(8)" ::: "memory");
    __builtin_amdgcn_s_barrier();

    for (int t = 0; t < NT; ++t) {
        const int bfi = t & 3;

        bf16x8 af[4], bfr[4];
#pragma unroll
        for (int i = 0; i < 4; i++)
            af[i] = *(const bf16x8*)(As[bfi] + (wm + i * 16 + lr) * 32 + rsw);
#pragma unroll
        for (int j = 0; j < 4; j++)
            bfr[j] = *(const bf16x8*)(Bs[bfi] + (wn + j * 16 + lr) * 32 + rsw);

        if (t + 3 < NT) STAGEV((t + 3) & 3, (t + 3) * 32);

        const int rem = NT - 1 - t;
        if (rem >= 3)      asm volatile("s_waitcnt vmcnt(8)" ::: "memory");
        else if (rem == 2) asm volatile("s_waitcnt vmcnt(4)" ::: "memory");
        else if (rem == 1) asm volatile("s_waitcnt vmcnt(0)" ::: "memory");
        __builtin_amdgcn_s_barrier();
        __builtin_amdgcn_sched_barrier(0);

        __builtin_amdgcn_s_setprio(1);
#pragma unroll
        for (int i = 0; i < 4; i++)
#pragma unroll
            for (int j = 0; j < 4; j++)
                acc[i][j] = __builtin_amdgcn_mfma_f32_16x16x32_bf16(
                    af[i], bfr[j], acc[i][j], 0, 0, 0);
        __builtin_amdgcn_s_setprio(0);
        __builtin_amdgcn_s_barrier();
    }
#undef STAGEV

#pragma unroll
    for (int j = 0; j < 4; j++) {
        const int col = n0 + wn + j * 16 + lr;
        const float bb = bias[col];
#pragma unroll
        for (int i = 0; i < 4; i++) {
            const int rowb = m0 + wm + i * 16 + lq * 4;
#pragma unroll
            for (int r = 0; r < 4; r++)
                C[(size_t)bz * sC + (size_t)(rowb + r) * N + col] =
                    acc[i][j][r] * scale + bb;
        }
    }
}

// ---------------------------------------------------------------- softmax
__global__ __launch_bounds__(256) void softmax_causal(
    const bf16* __restrict__ Sc, bf16* __restrict__ P, int S) {
    const int row = blockIdx.x;          // b*S + q
    const int q = row & (S - 1);
    const bf16* src = Sc + (size_t)row * S;
    bf16* dst = P + (size_t)row * S;
    const int L = q + 1;
    const int tid = threadIdx.x;
    const int k0 = tid * 8;

    bf16x8 u = ((const bf16x8*)src)[tid];
    float v[8];
    float mx = -3.0e38f;
#pragma unroll
    for (int i = 0; i < 8; i++) {
        v[i] = (k0 + i < L) ? (float)u[i] : -3.0e38f;
        mx = fmaxf(mx, v[i]);
    }
#pragma unroll
    for (int off = 32; off > 0; off >>= 1) mx = fmaxf(mx, __shfl_xor(mx, off, 64));
    __shared__ float redm[4], reds[4];
    if ((tid & 63) == 0) redm[tid >> 6] = mx;
    __syncthreads();
    mx = fmaxf(fmaxf(redm[0], redm[1]), fmaxf(redm[2], redm[3]));

    float sum = 0.f;
#pragma unroll
    for (int i = 0; i < 8; i++) {
        float e = (v[i] > -1.0e38f) ? __expf(v[i] - mx) : 0.f;
        v[i] = e;
        sum += e;
    }
#pragma unroll
    for (int off = 32; off > 0; off >>= 1) sum += __shfl_xor(sum, off, 64);
    if ((tid & 63) == 0) reds[tid >> 6] = sum;
    __syncthreads();
    sum = reds[0] + reds[1] + reds[2] + reds[3];
    const float inv = 1.0f / sum;
    bf16x8 o;
#pragma unroll
    for (int i = 0; i < 8; i++) o[i] = (bf16)(v[i] * inv);
    ((bf16x8*)dst)[tid] = o;
}

// ---------------------------------------------------------------- launch
extern "C" void kernel_launch(void* const* d_in, const int* in_sizes, int n_in,
                              void* d_out, int out_size, void* d_ws, size_t ws_size,
                              hipStream_t stream) {
    const int B = 4, S = 2048, E = 1024;
    const size_t SBE = (size_t)B * S * E;   // 8,388,608
    const size_t EE = (size_t)E * E;        // 1,048,576

    const float* q_in = (const float*)d_in[0];
    const float* k_in = (const float*)d_in[1];
    const float* v_in = (const float*)d_in[2];
    // d_in[3] = mask (tril) — causality handled by index math
    const float* Wq = (const float*)d_in[4];
    const float* bq = (const float*)d_in[5];
    const float* Wk = (const float*)d_in[6];
    const float* bk = (const float*)d_in[7];
    const float* Wv = (const float*)d_in[8];
    const float* bv = (const float*)d_in[9];
    const float* Wo = (const float*)d_in[10];
    const float* bo = (const float*)d_in[11];

    char* ws = (char*)d_ws;
    // Region A (67 MB), time-multiplexed:
    //   [0,48M): qkvb (phase 1), then Sc bf16 [0,33.5M) (phase 2)
    //   [48M,50M): WvT (bf16 Wv^T, live during Wvo prep)
    //   [50M,+4KB): bout
    bf16* qkvb = (bf16*)ws;
    bf16* Sc = (bf16*)ws;
    bf16* WvT = (bf16*)(ws + 3 * SBE * 2);
    float* bout = (float*)(ws + 3 * SBE * 2 + EE * 2);
    char* p = ws + (size_t)B * S * S * 4;
    bf16* QKVb = (bf16*)p; p += 3 * SBE * 2;   // Qb|Kb|VW contiguous
    bf16* VWt = (bf16*)p; p += SBE * 2;
    bf16* Pb = (bf16*)p; p += (size_t)B * S * S * 2;
    bf16* Wb = (bf16*)p; p += 4 * EE * 2;      // Wq|Wk|Wv(->Wvo)|Wo

    bf16* Qb = QKVb;
    bf16* Kb = QKVb + SBE;
    bf16* VW = QKVb + 2 * SBE;
    bf16* Wob = Wb + 3 * EE;
    bf16* Wvo = Wb + 2 * EE;   // Wv slot overwritten by Wvo after transpose

    dim3 blk(256), blk512(512);

    // 1. converts
    dim3 gcvt3((int)(SBE / 4 / 256), 1, 3);
    cvt3_f32_to_bf16<<<gcvt3, blk, 0, stream>>>(q_in, k_in, v_in, qkvb, (int)(SBE / 4));
    dim3 gcvt4((int)(EE / 4 / 256), 1, 4);
    cvt4_f32_to_bf16<<<gcvt4, blk, 0, stream>>>(Wq, Wk, Wv, Wo, Wb, (int)(EE / 4));

    // 2. WvT = Wv^T ; Wvo = Wo @ Wv (B^T GEMM with B=WvT) ; bout = Wo bv + bo
    dim3 gtw(16, 16, 1);
    transpose_bf16<<<gtw, blk, 0, stream>>>((const unsigned short*)(Wb + 2 * EE),
                                            (unsigned short*)WvT, E, E);
    dim3 gwvo(E / 128, E / 128, 1);
    gemm_bt128<0><<<gwvo, blk, 0, stream>>>(Wob, WvT, nullptr, nullptr, nullptr,
                                            Wvo, E, E, E, 0, 0, 0, 1.f);
    bias_fold<<<256, blk, 0, stream>>>(Wo, bv, bo, bout);

    // 3. fused projections: z=0 Q (bq), z=1 K (bk), z=2 VW = v_in @ Wvo^T
    dim3 gproj(E / 256, (B * S) / 128, 3);
    gemm_pipe<0><<<gproj, blk512, 0, stream>>>(qkvb, Wb, bq, bk, nullptr, QKVb,
                                               B * S, E, E,
                                               (long long)SBE, (long long)EE,
                                               (long long)SBE, 1.f, 0);

    // 4. VW^T per batch: [S,E] -> [E,S]
    dim3 gt(E / 64, S / 64, B);
    transpose_bf16<<<gt, blk, 0, stream>>>((const unsigned short*)VW,
                                           (unsigned short*)VWt, S, E);

    // 5. scores = Q K^T / 32 -> bf16 (balanced causal skip)
    dim3 gsc(S / 256, S / 128, B);
    gemm_pipe<0><<<gsc, blk512, 0, stream>>>(Qb, Kb, nullptr, nullptr, nullptr, Sc,
                                             S, S, E,
                                             (long long)S * E, (long long)S * E,
                                             (long long)S * S, 0.03125f, 1);

    // 6. causal softmax -> bf16 probs (zeros above diagonal)
    softmax_causal<<<B * S, blk, 0, stream>>>(Sc, Pb, S);

    // 7. out = P @ VW + bout, causal K-trim (Keff = m0+128), 2 blocks/CU
    //    (long+short blocks pair on a CU), XCD-pair-balanced.
    dim3 gpv(E / 128, S / 128, B);
    gemm_pv128<<<gpv, blk, 0, stream>>>(Pb, VWt, bout, (float*)d_out, S, E, S,
                                        (long long)S * S, (long long)E * S,
                                        (long long)S * E, 1.f);
}